// Round 2
// baseline (5416.925 us; speedup 1.0000x reference)
//
#include <hip/hip_runtime.h>
#include <cstdint>

#define T_LEN 128
#define DA    16
#define DZ    32
#define HH    128

__device__ __forceinline__ float sigm(float x){ return 1.0f/(1.0f + __expf(-x)); }
__device__ __forceinline__ float tanh_f(float x){ return 1.0f - 2.0f/(__expf(2.0f*x)+1.0f); }

// ws layout (fp32 words):
//   [0,8192)         WihT0: float4 idx (k4*512+g), k4<4  -> Wih0[g][4*k4+kk]
//   [8192,73728)     WhhT0: k4<32
//   [73728,139264)   WihT1: k4<32
//   [139264,204800)  WhhT1: k4<32
//   [204800,205312)  b0 = bih0+bhh0
//   [205312,205824)  b1 = bih1+bhh1
//   [205824,402432)  alpha (512,128,3)

__global__ void prep_kernel(const float* __restrict__ Wih0, const float* __restrict__ Whh0,
                            const float* __restrict__ bih0, const float* __restrict__ bhh0,
                            const float* __restrict__ Wih1, const float* __restrict__ Whh1,
                            const float* __restrict__ bih1, const float* __restrict__ bhh1,
                            float* __restrict__ ws) {
  int idx = blockIdx.x*256 + threadIdx.x;
  if (idx < 8192) {
    int k4 = idx >> 11, g = (idx >> 2) & 511, kk = idx & 3;
    ws[idx] = Wih0[g*DA + k4*4 + kk];
  } else if (idx < 73728) {
    int f = idx - 8192;
    int k4 = f >> 11, g = (f >> 2) & 511, kk = f & 3;
    ws[idx] = Whh0[g*HH + k4*4 + kk];
  } else if (idx < 139264) {
    int f = idx - 73728;
    int k4 = f >> 11, g = (f >> 2) & 511, kk = f & 3;
    ws[idx] = Wih1[g*HH + k4*4 + kk];
  } else if (idx < 204800) {
    int f = idx - 139264;
    int k4 = f >> 11, g = (f >> 2) & 511, kk = f & 3;
    ws[idx] = Whh1[g*HH + k4*4 + kk];
  } else if (idx < 205312) {
    int j = idx - 204800;
    ws[idx] = bih0[j] + bhh0[j];
  } else if (idx < 205824) {
    int j = idx - 205312;
    ws[idx] = bih1[j] + bhh1[j];
  }
}

// Persistent 2-layer LSTM + softmax head, fp32 weights. One block = 2 batch rows.
__global__ __launch_bounds__(256) void lstm_kernel(
    const float* __restrict__ a, const float* __restrict__ a0,
    const float* __restrict__ ws, const float* __restrict__ Wlin,
    const float* __restrict__ blin, float* __restrict__ alpha_out) {
  const float4* Wih0p = (const float4*)(ws);
  const float4* Whh0p = (const float4*)(ws + 8192);
  const float4* Wih1p = (const float4*)(ws + 73728);
  const float4* Whh1p = (const float4*)(ws + 139264);
  const float* b0v = ws + 204800;
  const float* b1v = ws + 205312;

  __shared__ __align__(16) float sx[2][T_LEN][DA];
  __shared__ __align__(16) float sh0[2][HH];
  __shared__ __align__(16) float sh1[2][HH];
  __shared__ float sc0[2][HH], sc1[2][HH];
  __shared__ float gates[2][4*HH];
  __shared__ float sWl[3][HH];
  __shared__ float partial[4][3];

  int tid = threadIdx.x;
  int bb = blockIdx.x * 2;
  for (int i = tid; i < 2*T_LEN*DA; i += 256) {
    int r = i / (T_LEN*DA), rem = i % (T_LEN*DA), t = rem / DA, d = rem % DA;
    sx[r][t][d] = (t == 0) ? a0[d] : a[((size_t)(bb + r)*T_LEN + (t-1))*DA + d];
  }
  for (int i = tid; i < 3*HH; i += 256) sWl[i/HH][i%HH] = Wlin[i];
  if (tid < 2*HH) { int r = tid>>7, j = tid&127; sh0[r][j]=0.f; sc0[r][j]=0.f; sh1[r][j]=0.f; sc1[r][j]=0.f; }
  float bi0a = b0v[tid], bi0b = b0v[tid+256];
  float bi1a = b1v[tid], bi1b = b1v[tid+256];
  __syncthreads();

  #pragma unroll 1
  for (int t = 0; t < T_LEN; ++t) {
    // ---- layer 0: gates g=tid and g=tid+256, batch rows 0,1 ----
    float aA0 = bi0a, aA1 = bi0a, aB0 = bi0b, aB1 = bi0b;
    #pragma unroll
    for (int k4 = 0; k4 < 4; ++k4) {
      float4 w0 = Wih0p[k4*512 + tid];
      float4 w1 = Wih0p[k4*512 + 256 + tid];
      float4 x0 = *(const float4*)&sx[0][t][4*k4];
      float4 x1 = *(const float4*)&sx[1][t][4*k4];
      aA0 += w0.x*x0.x + w0.y*x0.y + w0.z*x0.z + w0.w*x0.w;
      aA1 += w0.x*x1.x + w0.y*x1.y + w0.z*x1.z + w0.w*x1.w;
      aB0 += w1.x*x0.x + w1.y*x0.y + w1.z*x0.z + w1.w*x0.w;
      aB1 += w1.x*x1.x + w1.y*x1.y + w1.z*x1.z + w1.w*x1.w;
    }
    #pragma unroll 8
    for (int k4 = 0; k4 < 32; ++k4) {
      float4 w0 = Whh0p[k4*512 + tid];
      float4 w1 = Whh0p[k4*512 + 256 + tid];
      float4 h0 = *(const float4*)&sh0[0][4*k4];
      float4 h1 = *(const float4*)&sh0[1][4*k4];
      aA0 += w0.x*h0.x + w0.y*h0.y + w0.z*h0.z + w0.w*h0.w;
      aA1 += w0.x*h1.x + w0.y*h1.y + w0.z*h1.z + w0.w*h1.w;
      aB0 += w1.x*h0.x + w1.y*h0.y + w1.z*h0.z + w1.w*h0.w;
      aB1 += w1.x*h1.x + w1.y*h1.y + w1.z*h1.z + w1.w*h1.w;
    }
    gates[0][tid]=aA0; gates[1][tid]=aA1; gates[0][tid+256]=aB0; gates[1][tid+256]=aB1;
    __syncthreads();
    {
      int r = tid>>7, j = tid&127;
      float ig = gates[r][j], fg = gates[r][j+HH], gg = gates[r][j+2*HH], og = gates[r][j+3*HH];
      float c = sigm(fg)*sc0[r][j] + sigm(ig)*tanh_f(gg);
      sc0[r][j] = c;
      sh0[r][j] = sigm(og)*tanh_f(c);
    }
    __syncthreads();
    // ---- layer 1 ----
    aA0 = bi1a; aA1 = bi1a; aB0 = bi1b; aB1 = bi1b;
    #pragma unroll 8
    for (int k4 = 0; k4 < 32; ++k4) {
      float4 w0 = Wih1p[k4*512 + tid];
      float4 w1 = Wih1p[k4*512 + 256 + tid];
      float4 h0 = *(const float4*)&sh0[0][4*k4];
      float4 h1 = *(const float4*)&sh0[1][4*k4];
      aA0 += w0.x*h0.x + w0.y*h0.y + w0.z*h0.z + w0.w*h0.w;
      aA1 += w0.x*h1.x + w0.y*h1.y + w0.z*h1.z + w0.w*h1.w;
      aB0 += w1.x*h0.x + w1.y*h0.y + w1.z*h0.z + w1.w*h0.w;
      aB1 += w1.x*h1.x + w1.y*h1.y + w1.z*h1.z + w1.w*h1.w;
    }
    #pragma unroll 8
    for (int k4 = 0; k4 < 32; ++k4) {
      float4 w0 = Whh1p[k4*512 + tid];
      float4 w1 = Whh1p[k4*512 + 256 + tid];
      float4 h0 = *(const float4*)&sh1[0][4*k4];
      float4 h1 = *(const float4*)&sh1[1][4*k4];
      aA0 += w0.x*h0.x + w0.y*h0.y + w0.z*h0.z + w0.w*h0.w;
      aA1 += w0.x*h1.x + w0.y*h1.y + w0.z*h1.z + w0.w*h1.w;
      aB0 += w1.x*h0.x + w1.y*h0.y + w1.z*h0.z + w1.w*h0.w;
      aB1 += w1.x*h1.x + w1.y*h1.y + w1.z*h1.z + w1.w*h1.w;
    }
    gates[0][tid]=aA0; gates[1][tid]=aA1; gates[0][tid+256]=aB0; gates[1][tid+256]=aB1;
    __syncthreads();
    {
      int r = tid>>7, j = tid&127;
      float ig = gates[r][j], fg = gates[r][j+HH], gg = gates[r][j+2*HH], og = gates[r][j+3*HH];
      float c = sigm(fg)*sc1[r][j] + sigm(ig)*tanh_f(gg);
      sc1[r][j] = c;
      sh1[r][j] = sigm(og)*tanh_f(c);
    }
    __syncthreads();
    // ---- alpha = softmax(h1 @ Wlin^T + blin) ----
    {
      int wv = tid>>6, lane = tid&63, r = wv>>1, jo = (wv&1)*64;
      float hv = sh1[r][jo+lane];
      float p0 = hv*sWl[0][jo+lane], p1 = hv*sWl[1][jo+lane], p2 = hv*sWl[2][jo+lane];
      #pragma unroll
      for (int off = 32; off > 0; off >>= 1) {
        p0 += __shfl_down(p0, off); p1 += __shfl_down(p1, off); p2 += __shfl_down(p2, off);
      }
      if (lane == 0) { partial[wv][0]=p0; partial[wv][1]=p1; partial[wv][2]=p2; }
    }
    __syncthreads();
    if (tid < 2) {
      float l0 = partial[2*tid][0]+partial[2*tid+1][0]+blin[0];
      float l1 = partial[2*tid][1]+partial[2*tid+1][1]+blin[1];
      float l2 = partial[2*tid][2]+partial[2*tid+1][2]+blin[2];
      float m = fmaxf(l0, fmaxf(l1, l2));
      float e0=__expf(l0-m), e1=__expf(l1-m), e2=__expf(l2-m);
      float inv = 1.0f/(e0+e1+e2);
      float* dst = alpha_out + (((size_t)(bb+tid))*T_LEN + t)*3;
      dst[0]=e0*inv; dst[1]=e1*inv; dst[2]=e2*inv;
    }
    __syncthreads();
  }
}

// Kalman scan: one single-wave block per batch chain. Dead-simple scalar phases,
// padded LDS strides, no symmetry assumptions, no reinterpret casts.
__global__ __launch_bounds__(64) void kalman_kernel(
    const float* __restrict__ a, const float* __restrict__ A,
    const float* __restrict__ C, const float* __restrict__ alpha,
    float* __restrict__ out) {
  __shared__ float Sig[2][DZ][DZ+1];
  __shared__ float Am[DZ][DZ+1];
  __shared__ float Cm[DA][DZ+1];
  __shared__ float Nn[DZ][DA+1];   // N = Sigma_pred @ C^T
  __shared__ float Aug[DA][34];    // [S | I]
  __shared__ float Kgm[DZ][DA+1];
  __shared__ float Mm[DA][DZ+1];   // M = C @ Sigma_pred
  __shared__ float Sp2[DZ][DZ+1];  // Sigma'
  __shared__ float T2m[DZ][DZ+1];
  __shared__ float muv[DZ], mun[DZ], rv[DA], atv[DA];

  int l = threadIdx.x;
  int b = blockIdx.x;
  for (int e = l; e < DZ*(DZ+1); e += 64) (&Sig[0][0][0])[e] = 0.0f;
  __syncthreads();
  if (l < DZ) { Sig[0][l][l] = 1.0f; muv[l] = 0.0f; }
  __syncthreads();

  const float* alb = alpha + (size_t)b*T_LEN*3;

  #pragma unroll 1
  for (int t = 0; t < T_LEN; ++t) {
    int ta = (t < T_LEN-1) ? t+1 : t;
    float a10 = alb[ta*3+0], a11 = alb[ta*3+1], a12 = alb[ta*3+2];
    float a00 = alb[t*3+0],  a01 = alb[t*3+1],  a02 = alb[t*3+2];
    float (*Sp)[DZ+1] = Sig[t & 1];
    float (*Sn)[DZ+1] = Sig[(t & 1) ^ 1];

    // Phase A: A_next = sum_k alpha[t+1,k] A[k,t+1]; C_mix = sum_k alpha[t,k] C[k,t]
    {
      const float* A0b = A + (size_t)(0*T_LEN + ta)*DZ*DZ;
      const float* A1b = A + (size_t)(1*T_LEN + ta)*DZ*DZ;
      const float* A2b = A + (size_t)(2*T_LEN + ta)*DZ*DZ;
      for (int e = l; e < DZ*DZ; e += 64) {
        int i = e >> 5, j = e & 31;
        Am[i][j] = a10*A0b[e] + a11*A1b[e] + a12*A2b[e];
      }
      const float* C0b = C + (size_t)(0*T_LEN + t)*DA*DZ;
      const float* C1b = C + (size_t)(1*T_LEN + t)*DA*DZ;
      const float* C2b = C + (size_t)(2*T_LEN + t)*DA*DZ;
      for (int e = l; e < DA*DZ; e += 64) {
        int i = e >> 5, j = e & 31;
        Cm[i][j] = a00*C0b[e] + a01*C1b[e] + a02*C2b[e];
      }
      if (l < DA) atv[l] = a[((size_t)b*T_LEN + t)*DA + l];
    }
    __syncthreads();

    // N = Sigma_pred @ C^T (32x16); r = a_t - C @ mu_pred
    for (int e = l; e < DZ*DA; e += 64) {
      int i = e >> 4, j = e & 15;
      float acc = 0.0f;
      #pragma unroll
      for (int k = 0; k < DZ; ++k) acc += Sp[i][k]*Cm[j][k];
      Nn[i][j] = acc;
    }
    if (l < DA) {
      float acc = atv[l];
      #pragma unroll
      for (int k = 0; k < DZ; ++k) acc -= Cm[l][k]*muv[k];
      rv[l] = acc;
    }
    __syncthreads();

    // Aug = [S | I], S = C @ N + 0.01 I
    for (int e = l; e < DA*32; e += 64) {
      int i = e >> 5, j = e & 31;
      float v;
      if (j < DA) {
        float acc = 0.0f;
        #pragma unroll
        for (int k = 0; k < DZ; ++k) acc += Cm[i][k]*Nn[k][j];
        v = acc + ((i == j) ? 0.01f : 0.0f);
      } else {
        v = ((j - DA) == i) ? 1.0f : 0.0f;
      }
      Aug[i][j] = v;
    }
    __syncthreads();

    // Gauss-Jordan (S is SPD; no pivoting). read-all / barrier / write-all per pivot.
    #pragma unroll 1
    for (int p = 0; p < DA; ++p) {
      int c = l & 31, rb = l >> 5;
      float pinv = 1.0f / Aug[p][p];
      float pc = Aug[p][c];
      float ov[8], fv[8];
      #pragma unroll
      for (int s = 0; s < 8; ++s) { int row = rb + 2*s; ov[s] = Aug[row][c]; fv[s] = Aug[row][p]; }
      __syncthreads();
      #pragma unroll
      for (int s = 0; s < 8; ++s) {
        int row = rb + 2*s;
        Aug[row][c] = (row == p) ? (ov[s]*pinv) : (ov[s] - fv[s]*(pinv*pc));
      }
      __syncthreads();
    }

    // Kg = N @ Sinv (32x16)
    for (int e = l; e < DZ*DA; e += 64) {
      int i = e >> 4, j = e & 15;
      float acc = 0.0f;
      #pragma unroll
      for (int k = 0; k < DA; ++k) acc += Nn[i][k]*Aug[k][DA + j];
      Kgm[i][j] = acc;
    }
    __syncthreads();

    // mu = mu_pred + Kg @ r (output); M = C @ Sigma_pred
    if (l < DZ) {
      float acc = muv[l];
      #pragma unroll
      for (int k = 0; k < DA; ++k) acc += Kgm[l][k]*rv[k];
      mun[l] = acc;
      out[((size_t)b*T_LEN + t)*DZ + l] = acc;
    }
    for (int e = l; e < DA*DZ; e += 64) {
      int i = e >> 5, j = e & 31;
      float acc = 0.0f;
      #pragma unroll
      for (int k = 0; k < DZ; ++k) acc += Cm[i][k]*Sp[k][j];
      Mm[i][j] = acc;
    }
    __syncthreads();

    // Sigma' = Sigma_pred - Kg @ M
    for (int e = l; e < DZ*DZ; e += 64) {
      int i = e >> 5, j = e & 31;
      float acc = Sp[i][j];
      #pragma unroll
      for (int k = 0; k < DA; ++k) acc -= Kgm[i][k]*Mm[k][j];
      Sp2[i][j] = acc;
    }
    __syncthreads();

    // T2 = A_next @ Sigma'
    for (int e = l; e < DZ*DZ; e += 64) {
      int i = e >> 5, j = e & 31;
      float acc = 0.0f;
      #pragma unroll
      for (int k = 0; k < DZ; ++k) acc += Am[i][k]*Sp2[k][j];
      T2m[i][j] = acc;
    }
    __syncthreads();

    // Sigma_next = T2 @ A_next^T + 0.01 I ; mu_next = A_next @ mu
    for (int e = l; e < DZ*DZ; e += 64) {
      int i = e >> 5, j = e & 31;
      float acc = (i == j) ? 0.01f : 0.0f;
      #pragma unroll
      for (int k = 0; k < DZ; ++k) acc += T2m[i][k]*Am[j][k];
      Sn[i][j] = acc;
    }
    if (l < DZ) {
      float acc = 0.0f;
      #pragma unroll
      for (int k = 0; k < DZ; ++k) acc += Am[l][k]*mun[k];
      muv[l] = acc;
    }
    __syncthreads();
  }
}

extern "C" void kernel_launch(void* const* d_in, const int* in_sizes, int n_in,
                              void* d_out, int out_size, void* d_ws, size_t ws_size,
                              hipStream_t stream) {
  const float* a    = (const float*)d_in[0];
  const float* A    = (const float*)d_in[1];
  const float* C    = (const float*)d_in[2];
  const float* a0   = (const float*)d_in[3];
  const float* Wih0 = (const float*)d_in[4];
  const float* Whh0 = (const float*)d_in[5];
  const float* bih0 = (const float*)d_in[6];
  const float* bhh0 = (const float*)d_in[7];
  const float* Wih1 = (const float*)d_in[8];
  const float* Whh1 = (const float*)d_in[9];
  const float* bih1 = (const float*)d_in[10];
  const float* bhh1 = (const float*)d_in[11];
  const float* Wlin = (const float*)d_in[12];
  const float* blin = (const float*)d_in[13];
  float* ws = (float*)d_ws;
  float* alpha = ws + 205824;
  float* out = (float*)d_out;

  prep_kernel<<<804, 256, 0, stream>>>(Wih0, Whh0, bih0, bhh0, Wih1, Whh1, bih1, bhh1, ws);
  lstm_kernel<<<256, 256, 0, stream>>>(a, a0, ws, Wlin, blin, alpha);
  kalman_kernel<<<512, 64, 0, stream>>>(a, A, C, alpha, out);
}

// Round 3
// 2944.697 us; speedup vs baseline: 1.8396x; 1.8396x over previous
//
#include <hip/hip_runtime.h>
#include <cstdint>

#define T_LEN 128
#define DA    16
#define DZ    32
#define HH    128

__device__ __forceinline__ float sigm(float x){ return 1.0f/(1.0f + __expf(-x)); }
__device__ __forceinline__ float tanh_f(float x){ return 1.0f - 2.0f/(__expf(2.0f*x)+1.0f); }
__device__ __forceinline__ float dot4(float4 a, float4 b){ return a.x*b.x + a.y*b.y + a.z*b.z + a.w*b.w; }

// ws layout (fp32 words):
//   [0,8192)         WihT0: float4 idx (k4*512+g), k4<4  -> Wih0[g][4*k4+kk]
//   [8192,73728)     WhhT0: k4<32
//   [73728,139264)   WihT1: k4<32
//   [139264,204800)  WhhT1: k4<32
//   [204800,205312)  b0 = bih0+bhh0
//   [205312,205824)  b1 = bih1+bhh1
//   [205824,402432)  alpha (512,128,3)

__global__ void prep_kernel(const float* __restrict__ Wih0, const float* __restrict__ Whh0,
                            const float* __restrict__ bih0, const float* __restrict__ bhh0,
                            const float* __restrict__ Wih1, const float* __restrict__ Whh1,
                            const float* __restrict__ bih1, const float* __restrict__ bhh1,
                            float* __restrict__ ws) {
  int idx = blockIdx.x*256 + threadIdx.x;
  if (idx < 8192) {
    int k4 = idx >> 11, g = (idx >> 2) & 511, kk = idx & 3;
    ws[idx] = Wih0[g*DA + k4*4 + kk];
  } else if (idx < 73728) {
    int f = idx - 8192;
    int k4 = f >> 11, g = (f >> 2) & 511, kk = f & 3;
    ws[idx] = Whh0[g*HH + k4*4 + kk];
  } else if (idx < 139264) {
    int f = idx - 73728;
    int k4 = f >> 11, g = (f >> 2) & 511, kk = f & 3;
    ws[idx] = Wih1[g*HH + k4*4 + kk];
  } else if (idx < 204800) {
    int f = idx - 139264;
    int k4 = f >> 11, g = (f >> 2) & 511, kk = f & 3;
    ws[idx] = Whh1[g*HH + k4*4 + kk];
  } else if (idx < 205312) {
    int j = idx - 204800;
    ws[idx] = bih0[j] + bhh0[j];
  } else if (idx < 205824) {
    int j = idx - 205312;
    ws[idx] = bih1[j] + bhh1[j];
  }
}

// Persistent 2-layer LSTM + softmax head, fp32 weights. One block = 2 batch rows.
// unroll 16 on the H-loops: deeper vmcnt batching for L2-latency hiding.
__global__ __launch_bounds__(256) void lstm_kernel(
    const float* __restrict__ a, const float* __restrict__ a0,
    const float* __restrict__ ws, const float* __restrict__ Wlin,
    const float* __restrict__ blin, float* __restrict__ alpha_out) {
  const float4* Wih0p = (const float4*)(ws);
  const float4* Whh0p = (const float4*)(ws + 8192);
  const float4* Wih1p = (const float4*)(ws + 73728);
  const float4* Whh1p = (const float4*)(ws + 139264);
  const float* b0v = ws + 204800;
  const float* b1v = ws + 205312;

  __shared__ __align__(16) float sx[2][T_LEN][DA];
  __shared__ __align__(16) float sh0[2][HH];
  __shared__ __align__(16) float sh1[2][HH];
  __shared__ float sc0[2][HH], sc1[2][HH];
  __shared__ float gates[2][4*HH];
  __shared__ float sWl[3][HH];
  __shared__ float partial[4][3];

  int tid = threadIdx.x;
  int bb = blockIdx.x * 2;
  for (int i = tid; i < 2*T_LEN*DA; i += 256) {
    int r = i / (T_LEN*DA), rem = i % (T_LEN*DA), t = rem / DA, d = rem % DA;
    sx[r][t][d] = (t == 0) ? a0[d] : a[((size_t)(bb + r)*T_LEN + (t-1))*DA + d];
  }
  for (int i = tid; i < 3*HH; i += 256) sWl[i/HH][i%HH] = Wlin[i];
  if (tid < 2*HH) { int r = tid>>7, j = tid&127; sh0[r][j]=0.f; sc0[r][j]=0.f; sh1[r][j]=0.f; sc1[r][j]=0.f; }
  float bi0a = b0v[tid], bi0b = b0v[tid+256];
  float bi1a = b1v[tid], bi1b = b1v[tid+256];
  __syncthreads();

  #pragma unroll 1
  for (int t = 0; t < T_LEN; ++t) {
    // ---- layer 0: gates g=tid and g=tid+256, batch rows 0,1 ----
    float aA0 = bi0a, aA1 = bi0a, aB0 = bi0b, aB1 = bi0b;
    #pragma unroll
    for (int k4 = 0; k4 < 4; ++k4) {
      float4 w0 = Wih0p[k4*512 + tid];
      float4 w1 = Wih0p[k4*512 + 256 + tid];
      float4 x0 = *(const float4*)&sx[0][t][4*k4];
      float4 x1 = *(const float4*)&sx[1][t][4*k4];
      aA0 += dot4(w0,x0); aA1 += dot4(w0,x1);
      aB0 += dot4(w1,x0); aB1 += dot4(w1,x1);
    }
    #pragma unroll 16
    for (int k4 = 0; k4 < 32; ++k4) {
      float4 w0 = Whh0p[k4*512 + tid];
      float4 w1 = Whh0p[k4*512 + 256 + tid];
      float4 h0 = *(const float4*)&sh0[0][4*k4];
      float4 h1 = *(const float4*)&sh0[1][4*k4];
      aA0 += dot4(w0,h0); aA1 += dot4(w0,h1);
      aB0 += dot4(w1,h0); aB1 += dot4(w1,h1);
    }
    gates[0][tid]=aA0; gates[1][tid]=aA1; gates[0][tid+256]=aB0; gates[1][tid+256]=aB1;
    __syncthreads();
    {
      int r = tid>>7, j = tid&127;
      float ig = gates[r][j], fg = gates[r][j+HH], gg = gates[r][j+2*HH], og = gates[r][j+3*HH];
      float c = sigm(fg)*sc0[r][j] + sigm(ig)*tanh_f(gg);
      sc0[r][j] = c;
      sh0[r][j] = sigm(og)*tanh_f(c);
    }
    __syncthreads();
    // ---- layer 1 ----
    aA0 = bi1a; aA1 = bi1a; aB0 = bi1b; aB1 = bi1b;
    #pragma unroll 16
    for (int k4 = 0; k4 < 32; ++k4) {
      float4 w0 = Wih1p[k4*512 + tid];
      float4 w1 = Wih1p[k4*512 + 256 + tid];
      float4 h0 = *(const float4*)&sh0[0][4*k4];
      float4 h1 = *(const float4*)&sh0[1][4*k4];
      aA0 += dot4(w0,h0); aA1 += dot4(w0,h1);
      aB0 += dot4(w1,h0); aB1 += dot4(w1,h1);
    }
    #pragma unroll 16
    for (int k4 = 0; k4 < 32; ++k4) {
      float4 w0 = Whh1p[k4*512 + tid];
      float4 w1 = Whh1p[k4*512 + 256 + tid];
      float4 h0 = *(const float4*)&sh1[0][4*k4];
      float4 h1 = *(const float4*)&sh1[1][4*k4];
      aA0 += dot4(w0,h0); aA1 += dot4(w0,h1);
      aB0 += dot4(w1,h0); aB1 += dot4(w1,h1);
    }
    gates[0][tid]=aA0; gates[1][tid]=aA1; gates[0][tid+256]=aB0; gates[1][tid+256]=aB1;
    __syncthreads();
    {
      int r = tid>>7, j = tid&127;
      float ig = gates[r][j], fg = gates[r][j+HH], gg = gates[r][j+2*HH], og = gates[r][j+3*HH];
      float c = sigm(fg)*sc1[r][j] + sigm(ig)*tanh_f(gg);
      sc1[r][j] = c;
      sh1[r][j] = sigm(og)*tanh_f(c);
    }
    __syncthreads();
    // ---- alpha = softmax(h1 @ Wlin^T + blin) ----
    {
      int wv = tid>>6, lane = tid&63, r = wv>>1, jo = (wv&1)*64;
      float hv = sh1[r][jo+lane];
      float p0 = hv*sWl[0][jo+lane], p1 = hv*sWl[1][jo+lane], p2 = hv*sWl[2][jo+lane];
      #pragma unroll
      for (int off = 32; off > 0; off >>= 1) {
        p0 += __shfl_down(p0, off); p1 += __shfl_down(p1, off); p2 += __shfl_down(p2, off);
      }
      if (lane == 0) { partial[wv][0]=p0; partial[wv][1]=p1; partial[wv][2]=p2; }
    }
    __syncthreads();
    if (tid < 2) {
      float l0 = partial[2*tid][0]+partial[2*tid+1][0]+blin[0];
      float l1 = partial[2*tid][1]+partial[2*tid+1][1]+blin[1];
      float l2 = partial[2*tid][2]+partial[2*tid+1][2]+blin[2];
      float m = fmaxf(l0, fmaxf(l1, l2));
      float e0=__expf(l0-m), e1=__expf(l1-m), e2=__expf(l2-m);
      float inv = 1.0f/(e0+e1+e2);
      float* dst = alpha_out + (((size_t)(bb+tid))*T_LEN + t)*3;
      dst[0]=e0*inv; dst[1]=e1*inv; dst[2]=e2*inv;
    }
    __syncthreads();
  }
}

// Kalman scan v2: 256 threads (4 waves) per chain, float4 k-loops, symmetry-based
// row-major-only matmuls (Sigma, Sigma', Sinv symmetric => B read row-wise).
__global__ __launch_bounds__(256) void kalman_kernel(
    const float* __restrict__ a, const float* __restrict__ A,
    const float* __restrict__ C, const float* __restrict__ alpha,
    float* __restrict__ out) {
  __shared__ __align__(16) float Sg[DZ][36];    // Sigma_pred (kept symmetric)
  __shared__ __align__(16) float Am[DZ][36];    // A_next mix
  __shared__ __align__(16) float Cm[DA][36];    // C mix
  __shared__ __align__(16) float Nn[DZ][20];    // N = Sigma_pred @ C^T
  __shared__ __align__(16) float NnT[DA][36];   // N^T
  __shared__ __align__(16) float Aug[DA][36];   // [S | I] -> [I | Sinv]
  __shared__ __align__(16) float Kg[DZ][20];    // Kalman gain
  __shared__ __align__(16) float Sp2[DZ][36];   // Sigma'
  __shared__ __align__(16) float T2m[DZ][36];   // A @ Sigma'
  __shared__ __align__(16) float sa[T_LEN][DA]; // observations for this chain
  __shared__ float salpha[T_LEN*3];
  __shared__ float muv[DZ], mun[DZ], rv[DA];

  int tid = threadIdx.x;
  int b = blockIdx.x;

  for (int e = tid; e < T_LEN*DA; e += 256) (&sa[0][0])[e] = a[(size_t)b*T_LEN*DA + e];
  for (int e = tid; e < T_LEN*3; e += 256) salpha[e] = alpha[(size_t)b*T_LEN*3 + e];
  for (int e = tid; e < DZ*36; e += 256) (&Sg[0][0])[e] = 0.0f;
  __syncthreads();
  if (tid < DZ) { Sg[tid][tid] = 1.0f; muv[tid] = 0.0f; }
  __syncthreads();

  const int i8 = tid >> 3, j4 = (tid & 7) * 4;     // 32x8 grid, 4-col tiles
  const int jA = tid & 7, jB = jA + 8;             // 32x16 via two cols
  const int i16 = tid >> 4, j16 = tid & 15;        // 16x16 grid

  #pragma unroll 1
  for (int t = 0; t < T_LEN; ++t) {
    int ta = (t < T_LEN-1) ? t+1 : t;
    float b10 = salpha[ta*3+0], b11 = salpha[ta*3+1], b12 = salpha[ta*3+2];
    float b00 = salpha[t*3+0],  b01 = salpha[t*3+1],  b02 = salpha[t*3+2];

    // ---- MIX: A_next (alpha[t+1]) and C_mix (alpha[t]) ----
    {
      const float4* A0 = (const float4*)(A + (size_t)(0*T_LEN + ta)*DZ*DZ);
      const float4* A1 = (const float4*)(A + (size_t)(1*T_LEN + ta)*DZ*DZ);
      const float4* A2 = (const float4*)(A + (size_t)(2*T_LEN + ta)*DZ*DZ);
      float4 v0 = A0[tid], v1 = A1[tid], v2 = A2[tid];
      float4 v;
      v.x = b10*v0.x + b11*v1.x + b12*v2.x;
      v.y = b10*v0.y + b11*v1.y + b12*v2.y;
      v.z = b10*v0.z + b11*v1.z + b12*v2.z;
      v.w = b10*v0.w + b11*v1.w + b12*v2.w;
      *(float4*)&Am[i8][j4] = v;
      if (tid < 128) {
        const float4* C0 = (const float4*)(C + (size_t)(0*T_LEN + t)*DA*DZ);
        const float4* C1 = (const float4*)(C + (size_t)(1*T_LEN + t)*DA*DZ);
        const float4* C2 = (const float4*)(C + (size_t)(2*T_LEN + t)*DA*DZ);
        float4 c0 = C0[tid], c1 = C1[tid], c2 = C2[tid];
        float4 c;
        c.x = b00*c0.x + b01*c1.x + b02*c2.x;
        c.y = b00*c0.y + b01*c1.y + b02*c2.y;
        c.z = b00*c0.z + b01*c1.z + b02*c2.z;
        c.w = b00*c0.w + b01*c1.w + b02*c2.w;
        *(float4*)&Cm[tid>>3][(tid&7)*4] = c;
      }
    }
    __syncthreads();

    // ---- N = Sigma_pred @ C^T (via Sigma symmetry); r = a_t - C @ mu_pred ----
    {
      float accA = 0.0f, accB = 0.0f;
      #pragma unroll
      for (int k4 = 0; k4 < 8; ++k4) {
        float4 s  = *(const float4*)&Sg[i8][k4*4];
        float4 cA = *(const float4*)&Cm[jA][k4*4];
        float4 cB = *(const float4*)&Cm[jB][k4*4];
        accA += dot4(s,cA); accB += dot4(s,cB);
      }
      Nn[i8][jA] = accA; Nn[i8][jB] = accB;
      NnT[jA][i8] = accA; NnT[jB][i8] = accB;
      if (tid < DA) {
        float acc = sa[t][tid];
        #pragma unroll
        for (int k = 0; k < DZ; ++k) acc -= Cm[tid][k]*muv[k];
        rv[tid] = acc;
      }
    }
    __syncthreads();

    // ---- Aug = [S | I],  S = C @ N + 0.01 I ----
    {
      float acc = 0.0f;
      #pragma unroll
      for (int k4 = 0; k4 < 8; ++k4) {
        float4 c = *(const float4*)&Cm[i16][k4*4];
        float4 n = *(const float4*)&NnT[j16][k4*4];
        acc += dot4(c,n);
      }
      Aug[i16][j16] = acc + ((i16 == j16) ? 0.01f : 0.0f);
      Aug[i16][16 + j16] = (i16 == j16) ? 1.0f : 0.0f;
    }
    __syncthreads();

    // ---- Gauss-Jordan inverse (S SPD, no pivoting) ----
    #pragma unroll 1
    for (int p = 0; p < DA; ++p) {
      float app  = Aug[p][p];
      float arp  = Aug[i16][p];
      float a0   = Aug[i16][j16],    a1   = Aug[i16][j16+16];
      float apc0 = Aug[p][j16],      apc1 = Aug[p][j16+16];
      __syncthreads();
      float pinv = 1.0f / app;
      if (i16 == p) { Aug[i16][j16] = a0*pinv;      Aug[i16][j16+16] = a1*pinv; }
      else { float f = arp*pinv;
             Aug[i16][j16] = a0 - f*apc0;           Aug[i16][j16+16] = a1 - f*apc1; }
      __syncthreads();
    }

    // ---- Kg = N @ Sinv (via Sinv symmetry: row j of right half) ----
    {
      float accA = 0.0f, accB = 0.0f;
      #pragma unroll
      for (int k4 = 0; k4 < 4; ++k4) {
        float4 n  = *(const float4*)&Nn[i8][k4*4];
        float4 sA = *(const float4*)&Aug[jA][16 + k4*4];
        float4 sB = *(const float4*)&Aug[jB][16 + k4*4];
        accA += dot4(n,sA); accB += dot4(n,sB);
      }
      Kg[i8][jA] = accA; Kg[i8][jB] = accB;
    }
    __syncthreads();

    // ---- mu = mu_pred + Kg r (write output); Sigma' = Sigma_pred - Kg N^T ----
    if (tid < DZ) {
      float m = muv[tid];
      #pragma unroll
      for (int k = 0; k < DA; ++k) m += Kg[tid][k]*rv[k];
      mun[tid] = m;
      out[((size_t)b*T_LEN + t)*DZ + tid] = m;
    }
    {
      float4 acc = *(const float4*)&Sg[i8][j4];
      #pragma unroll
      for (int k4 = 0; k4 < 4; ++k4) {
        float4 kg = *(const float4*)&Kg[i8][k4*4];
        float4 n0 = *(const float4*)&Nn[j4+0][k4*4];
        float4 n1 = *(const float4*)&Nn[j4+1][k4*4];
        float4 n2 = *(const float4*)&Nn[j4+2][k4*4];
        float4 n3 = *(const float4*)&Nn[j4+3][k4*4];
        acc.x -= dot4(kg,n0); acc.y -= dot4(kg,n1);
        acc.z -= dot4(kg,n2); acc.w -= dot4(kg,n3);
      }
      *(float4*)&Sp2[i8][j4] = acc;
    }
    __syncthreads();

    // ---- T2 = A_next @ Sigma' (via Sigma' symmetry) ----
    {
      float4 acc = make_float4(0.f,0.f,0.f,0.f);
      #pragma unroll
      for (int k4 = 0; k4 < 8; ++k4) {
        float4 am = *(const float4*)&Am[i8][k4*4];
        float4 s0 = *(const float4*)&Sp2[j4+0][k4*4];
        float4 s1 = *(const float4*)&Sp2[j4+1][k4*4];
        float4 s2 = *(const float4*)&Sp2[j4+2][k4*4];
        float4 s3 = *(const float4*)&Sp2[j4+3][k4*4];
        acc.x += dot4(am,s0); acc.y += dot4(am,s1);
        acc.z += dot4(am,s2); acc.w += dot4(am,s3);
      }
      *(float4*)&T2m[i8][j4] = acc;
    }
    __syncthreads();

    // ---- Sigma_next = T2 @ A_next^T + 0.01 I ; mu_next = A_next @ mu ----
    {
      float4 acc = make_float4(0.f,0.f,0.f,0.f);
      #pragma unroll
      for (int k4 = 0; k4 < 8; ++k4) {
        float4 t2 = *(const float4*)&T2m[i8][k4*4];
        float4 a0 = *(const float4*)&Am[j4+0][k4*4];
        float4 a1 = *(const float4*)&Am[j4+1][k4*4];
        float4 a2 = *(const float4*)&Am[j4+2][k4*4];
        float4 a3 = *(const float4*)&Am[j4+3][k4*4];
        acc.x += dot4(t2,a0); acc.y += dot4(t2,a1);
        acc.z += dot4(t2,a2); acc.w += dot4(t2,a3);
      }
      int d = i8 - j4;
      if (d >= 0 && d < 4) (&acc.x)[d] += 0.01f;
      *(float4*)&Sg[i8][j4] = acc;
    }
    if (tid < DZ) {
      float m = 0.0f;
      #pragma unroll
      for (int k = 0; k < DZ; ++k) m += Am[tid][k]*mun[k];
      muv[tid] = m;
    }
    __syncthreads();
  }
}

extern "C" void kernel_launch(void* const* d_in, const int* in_sizes, int n_in,
                              void* d_out, int out_size, void* d_ws, size_t ws_size,
                              hipStream_t stream) {
  const float* a    = (const float*)d_in[0];
  const float* A    = (const float*)d_in[1];
  const float* C    = (const float*)d_in[2];
  const float* a0   = (const float*)d_in[3];
  const float* Wih0 = (const float*)d_in[4];
  const float* Whh0 = (const float*)d_in[5];
  const float* bih0 = (const float*)d_in[6];
  const float* bhh0 = (const float*)d_in[7];
  const float* Wih1 = (const float*)d_in[8];
  const float* Whh1 = (const float*)d_in[9];
  const float* bih1 = (const float*)d_in[10];
  const float* bhh1 = (const float*)d_in[11];
  const float* Wlin = (const float*)d_in[12];
  const float* blin = (const float*)d_in[13];
  float* ws = (float*)d_ws;
  float* alpha = ws + 205824;
  float* out = (float*)d_out;

  prep_kernel<<<804, 256, 0, stream>>>(Wih0, Whh0, bih0, bhh0, Wih1, Whh1, bih1, bhh1, ws);
  lstm_kernel<<<256, 256, 0, stream>>>(a, a0, ws, Wlin, blin, alpha);
  kalman_kernel<<<512, 256, 0, stream>>>(a, A, C, alpha, out);
}